// Round 1
// baseline (836.366 us; speedup 1.0000x reference)
//
#include <hip/hip_runtime.h>
#include <hip/hip_bf16.h>

#define NE 8
#define DIN 1024
#define DHID 4096
#define DOUTD 1024
#define NTOK 32768
#define CAP (NTOK / NE)  // 4096 tokens per expert

typedef unsigned short u16;
typedef __attribute__((ext_vector_type(8))) short bf16x8;   // 8 bf16 = 4 VGPR
typedef __attribute__((ext_vector_type(4))) float f32x4;

__device__ __forceinline__ u16 f2bf(float x) {
  unsigned u = __builtin_bit_cast(unsigned, x);
  u += 0x7fffu + ((u >> 16) & 1u);   // RNE; inputs are finite normals
  return (u16)(u >> 16);
}

__device__ __forceinline__ float gelu_erf(float x) {
  return 0.5f * x * (1.0f + erff(x * 0.70710678118654752f));
}

__device__ __forceinline__ void async_ld16(const void* g, void* l) {
  __builtin_amdgcn_global_load_lds(
      (const __attribute__((address_space(1))) unsigned int*)g,
      (__attribute__((address_space(3))) unsigned int*)l, 16, 0, 0);
}

// ---------------- fp32 -> bf16, 8 elems/thread, exact-size grid ----------------
__global__ __launch_bounds__(256) void convert_bf16_kernel(const float* __restrict__ in,
                                                           u16* __restrict__ out) {
  size_t i = ((size_t)blockIdx.x * 256 + threadIdx.x) * 8;
  float4 a = *(const float4*)(in + i);
  float4 b = *(const float4*)(in + i + 4);
  uint4 o;
  o.x = (unsigned)f2bf(a.x) | ((unsigned)f2bf(a.y) << 16);
  o.y = (unsigned)f2bf(a.z) | ((unsigned)f2bf(a.w) << 16);
  o.z = (unsigned)f2bf(b.x) | ((unsigned)f2bf(b.y) << 16);
  o.w = (unsigned)f2bf(b.z) | ((unsigned)f2bf(b.w) << 16);
  *(uint4*)(out + i) = o;
}

// ------------- [E][K][N] fp32 -> [E][N][K] bf16 (64x64 LDS-tiled) -------------
__global__ __launch_bounds__(256) void transpose_bf16_kernel(const float* __restrict__ in,
                                                             u16* __restrict__ out,
                                                             int K, int N) {
  __shared__ __align__(16) u16 tile[64 * 72];  // pad 72 to spread banks
  const int e = blockIdx.z;
  const int n0 = blockIdx.x * 64;
  const int k0 = blockIdx.y * 64;
  const float* inp = in + (size_t)e * K * N;
  u16* outp = out + (size_t)e * N * K;
  const int t = threadIdx.x;
  const int kr = t >> 4;          // 0..15
  const int nc = (t & 15) * 4;    // 0..60
#pragma unroll
  for (int rr = 0; rr < 4; ++rr) {
    int kl = rr * 16 + kr;
    float4 v = *(const float4*)(inp + (size_t)(k0 + kl) * N + n0 + nc);
    tile[(nc + 0) * 72 + kl] = f2bf(v.x);
    tile[(nc + 1) * 72 + kl] = f2bf(v.y);
    tile[(nc + 2) * 72 + kl] = f2bf(v.z);
    tile[(nc + 3) * 72 + kl] = f2bf(v.w);
  }
  __syncthreads();
  const int nr = t >> 3;         // 0..31
  const int kc = (t & 7) * 8;    // 0..56
#pragma unroll
  for (int it = 0; it < 2; ++it) {
    int nl = it * 32 + nr;
    bf16x8 w = *(const bf16x8*)(tile + nl * 72 + kc);
    *(bf16x8*)(outp + (size_t)(n0 + nl) * K + k0 + kc) = w;
  }
}

// ---------------------------- grouped GEMM ----------------------------
// C[e] = A[e] (CAP x K, row-major bf16)  @  Bt[e]^T  (Bt is N x K row-major bf16)
// 128x128 tile, BK=64, 4 waves (2x2), each wave 64x64 via 16x16x32 MFMA.
// LDS XOR-swizzle (unit ^= row&7) applied via pre-swizzled global source
// (global_load_lds writes linearly) + swizzled ds_read (rule #21).
// MFMA operands swapped: acc[i][j] lane l reg r = C[m0+wm+j*16+(l&15)]
//                                                 [n0+wn+i*16+(l>>4)*4+r]
template <int K, int N, bool GELU_OUT>
__global__ __launch_bounds__(256) void moe_gemm_kernel(const u16* __restrict__ A,
                                                       const u16* __restrict__ Bt,
                                                       const float* __restrict__ bias,
                                                       void* __restrict__ Out) {
  __shared__ __align__(16) u16 lds_a[128 * 64];
  __shared__ __align__(16) u16 lds_b[128 * 64];
  const int e = blockIdx.z;
  const int m0 = blockIdx.y * 128;
  const int n0 = blockIdx.x * 128;
  const u16* Ae = A + (size_t)e * CAP * K;
  const u16* Be = Bt + (size_t)e * N * K;

  const int t = threadIdx.x;
  const int lane = t & 63;
  const int wv = t >> 6;
  const int wm = (wv >> 1) * 64;
  const int wn = (wv & 1) * 64;

  f32x4 acc[4][4] = {};

  const int sr = wv * 8 + (lane >> 3);  // staging row within 32-row chunk
  const int su = lane & 7;              // staging 16B-unit (swizzled position)
  const int g  = lane >> 4;
  const int rl = lane & 15;

  for (int kt = 0; kt < K / 64; ++kt) {
    if (kt) __syncthreads();            // prev tile fully consumed
    const int kb = kt * 64;
#pragma unroll
    for (int it = 0; it < 4; ++it) {
      int r = it * 32 + sr;
      int uo = su ^ (r & 7);            // inverse-swizzled source unit
      async_ld16(Ae + (size_t)(m0 + r) * K + kb + uo * 8,
                 lds_a + (it * 32 + wv * 8) * 64);
    }
#pragma unroll
    for (int it = 0; it < 4; ++it) {
      int r = it * 32 + sr;
      int uo = su ^ (r & 7);
      async_ld16(Be + (size_t)(n0 + r) * K + kb + uo * 8,
                 lds_b + (it * 32 + wv * 8) * 64);
    }
    __syncthreads();                    // compiler drains vmcnt(0) before barrier
#pragma unroll
    for (int kk = 0; kk < 64; kk += 32) {
      const int uu = (kk >> 3) + g;
      bf16x8 bfr[4], afr[4];
#pragma unroll
      for (int i = 0; i < 4; ++i) {
        int row = wn + i * 16 + rl;
        bfr[i] = *(const bf16x8*)(lds_b + row * 64 + ((uu ^ (row & 7)) << 3));
      }
#pragma unroll
      for (int j = 0; j < 4; ++j) {
        int row = wm + j * 16 + rl;
        afr[j] = *(const bf16x8*)(lds_a + row * 64 + ((uu ^ (row & 7)) << 3));
      }
#pragma unroll
      for (int i = 0; i < 4; ++i)
#pragma unroll
        for (int j = 0; j < 4; ++j)
          acc[i][j] = __builtin_amdgcn_mfma_f32_16x16x32_bf16(bfr[i], afr[j],
                                                              acc[i][j], 0, 0, 0);
    }
  }

  const float* be = bias + (size_t)e * N;
  const int mb = m0 + wm + rl;
  const int nb = n0 + wn + g * 4;
  if constexpr (GELU_OUT) {
    u16* Oe = (u16*)Out + (size_t)e * CAP * N;
#pragma unroll
    for (int j = 0; j < 4; ++j) {
      int m = mb + j * 16;
#pragma unroll
      for (int i = 0; i < 4; ++i) {
        int n = nb + i * 16;
        float4 bv = *(const float4*)(be + n);
        ushort4 o;
        o.x = f2bf(gelu_erf(acc[i][j][0] + bv.x));
        o.y = f2bf(gelu_erf(acc[i][j][1] + bv.y));
        o.z = f2bf(gelu_erf(acc[i][j][2] + bv.z));
        o.w = f2bf(gelu_erf(acc[i][j][3] + bv.w));
        *(ushort4*)(Oe + (size_t)m * N + n) = o;
      }
    }
  } else {
    float* Oe = (float*)Out + (size_t)e * CAP * N;
#pragma unroll
    for (int j = 0; j < 4; ++j) {
      int m = mb + j * 16;
#pragma unroll
      for (int i = 0; i < 4; ++i) {
        int n = nb + i * 16;
        float4 bv = *(const float4*)(be + n);
        float4 o;
        o.x = acc[i][j][0] + bv.x;
        o.y = acc[i][j][1] + bv.y;
        o.z = acc[i][j][2] + bv.z;
        o.w = acc[i][j][3] + bv.w;
        *(float4*)(Oe + (size_t)m * N + n) = o;
      }
    }
  }
}

extern "C" void kernel_launch(void* const* d_in, const int* in_sizes, int n_in,
                              void* d_out, int out_size, void* d_ws, size_t ws_size,
                              hipStream_t stream) {
  const float* x  = (const float*)d_in[0];
  // d_in[1] = expert_size (equal splits by construction; unused)
  const float* w1 = (const float*)d_in[2];
  const float* b1 = (const float*)d_in[3];
  const float* w2 = (const float*)d_in[4];
  const float* b2 = (const float*)d_in[5];
  float* out = (float*)d_out;

  char* wsp = (char*)d_ws;
  u16* x_bf = (u16*)(wsp);                             // 64 MiB
  u16* w1t  = (u16*)(wsp + (size_t)67108864);          // 64 MiB  [E][DHID][DIN]
  u16* w2t  = (u16*)(wsp + (size_t)134217728);         // 64 MiB  [E][DOUT][DHID]
  u16* h    = (u16*)(wsp + (size_t)201326592);         // 256 MiB [NTOK][DHID]

  convert_bf16_kernel<<<(NTOK * DIN) / (256 * 8), 256, 0, stream>>>(x, x_bf);
  transpose_bf16_kernel<<<dim3(DHID / 64, DIN / 64, NE), 256, 0, stream>>>(w1, w1t, DIN, DHID);
  transpose_bf16_kernel<<<dim3(DOUTD / 64, DHID / 64, NE), 256, 0, stream>>>(w2, w2t, DHID, DOUTD);

  moe_gemm_kernel<DIN, DHID, true>
      <<<dim3(DHID / 128, CAP / 128, NE), 256, 0, stream>>>(x_bf, w1t, b1, h);
  moe_gemm_kernel<DHID, DOUTD, false>
      <<<dim3(DOUTD / 128, CAP / 128, NE), 256, 0, stream>>>(h, w2t, b2, out);
}

// Round 2
// 781.898 us; speedup vs baseline: 1.0697x; 1.0697x over previous
//
#include <hip/hip_runtime.h>
#include <hip/hip_bf16.h>
#include <type_traits>

#define NE 8
#define DIN 1024
#define DHID 4096
#define DOUTD 1024
#define NTOK 32768
#define CAP (NTOK / NE)  // 4096 tokens per expert

typedef unsigned short u16;
typedef __attribute__((ext_vector_type(8))) short bf16x8;   // 8 bf16 = 4 VGPR
typedef __attribute__((ext_vector_type(4))) float f32x4;

__device__ __forceinline__ u16 f2bf(float x) {
  unsigned u = __builtin_bit_cast(unsigned, x);
  u += 0x7fffu + ((u >> 16) & 1u);   // RNE; inputs are finite normals
  return (u16)(u >> 16);
}

__device__ __forceinline__ float gelu_erf(float x) {
  return 0.5f * x * (1.0f + erff(x * 0.70710678118654752f));
}

__device__ __forceinline__ void async_ld16(const void* g, void* l) {
  __builtin_amdgcn_global_load_lds(
      (const __attribute__((address_space(1))) unsigned int*)g,
      (__attribute__((address_space(3))) unsigned int*)l, 16, 0, 0);
}

// ---------------- fp32 -> bf16, 8 elems/thread ----------------
__global__ __launch_bounds__(256) void convert_bf16_kernel(const float* __restrict__ in,
                                                           u16* __restrict__ out) {
  size_t i = ((size_t)blockIdx.x * 256 + threadIdx.x) * 8;
  float4 a = *(const float4*)(in + i);
  float4 b = *(const float4*)(in + i + 4);
  uint4 o;
  o.x = (unsigned)f2bf(a.x) | ((unsigned)f2bf(a.y) << 16);
  o.y = (unsigned)f2bf(a.z) | ((unsigned)f2bf(a.w) << 16);
  o.z = (unsigned)f2bf(b.x) | ((unsigned)f2bf(b.y) << 16);
  o.w = (unsigned)f2bf(b.z) | ((unsigned)f2bf(b.w) << 16);
  *(uint4*)(out + i) = o;
}

// ------------- [E][K][N] fp32 -> [E][N][K] bf16 (64x64 LDS-tiled) -------------
__global__ __launch_bounds__(256) void transpose_bf16_kernel(const float* __restrict__ in,
                                                             u16* __restrict__ out,
                                                             int K, int N) {
  __shared__ __align__(16) u16 tile[64 * 72];
  const int e = blockIdx.z;
  const int n0 = blockIdx.x * 64;
  const int k0 = blockIdx.y * 64;
  const float* inp = in + (size_t)e * K * N;
  u16* outp = out + (size_t)e * N * K;
  const int t = threadIdx.x;
  const int kr = t >> 4;
  const int nc = (t & 15) * 4;
#pragma unroll
  for (int rr = 0; rr < 4; ++rr) {
    int kl = rr * 16 + kr;
    float4 v = *(const float4*)(inp + (size_t)(k0 + kl) * N + n0 + nc);
    tile[(nc + 0) * 72 + kl] = f2bf(v.x);
    tile[(nc + 1) * 72 + kl] = f2bf(v.y);
    tile[(nc + 2) * 72 + kl] = f2bf(v.z);
    tile[(nc + 3) * 72 + kl] = f2bf(v.w);
  }
  __syncthreads();
  const int nr = t >> 3;
  const int kc = (t & 7) * 8;
#pragma unroll
  for (int it = 0; it < 2; ++it) {
    int nl = it * 32 + nr;
    bf16x8 w = *(const bf16x8*)(tile + nl * 72 + kc);
    *(bf16x8*)(outp + (size_t)(n0 + nl) * K + k0 + kc) = w;
  }
}

// ---------------------------- grouped GEMM, 256x256 tile ----------------------------
// C[e] = A[e] (CAP x K bf16 row-major) @ Bt[e]^T (Bt: N x K bf16 row-major).
// 8 waves (2M x 4N), per-wave output 128x64. BK=32, 4-deep LDS ring (4 x 32KiB),
// counted vmcnt (steady-state vmcnt(8), never 0) + raw s_barrier (T3+T4), setprio (T5).
// LDS tile layout: packed [128][64] bf16 (global row r, k -> row'=r&127,
// unit=(r>>7)*4+(k>>3)), XOR-swizzled unit ^= row'&7; applied via inverse-swizzled
// global source (global_load_lds writes linearly) + swizzled ds_read (rule #21).
// MFMA operands swapped: acc[j][i] lane l reg r = C[m0+wr*128+j*16+(l&15)]
//                                                 [n0+wc*64+i*16+(l>>4)*4+r]
template <int K, int N, bool GELU_OUT>
__global__ __launch_bounds__(512, 2) void moe_gemm256_kernel(
    const u16* __restrict__ A, const u16* __restrict__ Bt,
    const float* __restrict__ bias, void* __restrict__ Out) {
  extern __shared__ __align__(16) char smem[];
  constexpr int TX = N / 256;
  constexpr int NT = K / 32;

  const int bid = blockIdx.x;
  const int e = bid & 7;          // bijective XCD swizzle: nwg % 8 == 0, one expert per XCD
  const int idx = bid >> 3;
  const int ty = idx / TX;
  const int tx = idx % TX;
  const int m0 = ty * 256;
  const int n0 = tx * 256;

  const u16* Ae = A + (size_t)e * CAP * K;
  const u16* Be = Bt + (size_t)e * N * K;

  const int t = threadIdx.x;
  const int l = t & 63;
  const int w = t >> 6;
  const int wr = w >> 2;
  const int wc = w & 3;
  const int g = l >> 4;
  const int rl = l & 15;

  // staging: per-thread global element offsets (inverse-swizzled source, rule #21)
  const int ul = (l & 7) ^ (l >> 3);       // logical 16B-unit for this lane's linear LDS slot
  const int skk = (ul & 3) * 8;            // k offset within 32-K tile
  const int srhi = (ul >> 2) << 7;         // +128 rows if upper half
  size_t sa[2], sb[2];
  int chunkbase[2];
#pragma unroll
  for (int it = 0; it < 2; ++it) {
    int chunk = it * 8 + w;
    int rowp = chunk * 8 + (l >> 3);
    sa[it] = (size_t)(m0 + rowp + srhi) * K + skk;
    sb[it] = (size_t)(n0 + rowp + srhi) * K + skk;
    chunkbase[it] = chunk * 1024;
  }

  // fragment LDS byte offsets (swizzled reads)
  int aoff[8], boff[4];
#pragma unroll
  for (int j = 0; j < 8; ++j) {
    int rp = j * 16 + rl;
    aoff[j] = rp * 128 + (((wr * 4 + g) ^ (rl & 7)) << 4);
  }
#pragma unroll
  for (int i = 0; i < 4; ++i) {
    int rp = (wc & 1) * 64 + i * 16 + rl;
    boff[i] = 16384 + rp * 128 + ((((wc >> 1) * 4 + g) ^ (rl & 7)) << 4);
  }

  f32x4 acc[8][4] = {};

  auto stage = [&](int tt) {
    char* dst = smem + (size_t)(tt & 3) * 32768;
    const size_t kb = (size_t)tt * 32;
#pragma unroll
    for (int it = 0; it < 2; ++it)
      async_ld16(Ae + sa[it] + kb, dst + chunkbase[it]);
#pragma unroll
    for (int it = 0; it < 2; ++it)
      async_ld16(Be + sb[it] + kb, dst + 16384 + chunkbase[it]);
  };

  // prologue: 3 tiles staged (12 loads); wait oldest 4 (tile 0), barrier
  stage(0);
  stage(1);
  stage(2);
  asm volatile("s_waitcnt vmcnt(8)\n\ts_barrier" ::: "memory");

  auto kiter = [&](int tt, auto STG, auto WN) {
    if constexpr (decltype(STG)::value) stage(tt + 3);   // ring[(t+3)&3]=ring[(t-1)&3]: consumed
    const char* src = smem + (size_t)(tt & 3) * 32768;
    bf16x8 afr[8], bfr[4];
#pragma unroll
    for (int i = 0; i < 4; ++i) bfr[i] = *(const bf16x8*)(src + boff[i]);
#pragma unroll
    for (int j = 0; j < 8; ++j) afr[j] = *(const bf16x8*)(src + aoff[j]);
    __builtin_amdgcn_s_setprio(1);
#pragma unroll
    for (int j = 0; j < 8; ++j)
#pragma unroll
      for (int i = 0; i < 4; ++i)
        acc[j][i] = __builtin_amdgcn_mfma_f32_16x16x32_bf16(bfr[i], afr[j], acc[j][i], 0, 0, 0);
    __builtin_amdgcn_s_setprio(0);
    constexpr int WNv = decltype(WN)::value;
    if constexpr (WNv >= 0) {
      // fused wait+barrier in ONE volatile asm: nothing can slip between them
      asm volatile("s_waitcnt vmcnt(%0)\n\ts_barrier" :: "n"(WNv) : "memory");
    }
  };

  for (int tt = 0; tt < NT - 3; ++tt)
    kiter(tt, std::true_type{}, std::integral_constant<int, 8>{});
  kiter(NT - 3, std::false_type{}, std::integral_constant<int, 4>{});
  kiter(NT - 2, std::false_type{}, std::integral_constant<int, 0>{});
  kiter(NT - 1, std::false_type{}, std::integral_constant<int, -1>{});

  // epilogue
  const float* be = bias + (size_t)e * N;
  const int mb = m0 + wr * 128 + rl;
  const int nb = n0 + wc * 64 + g * 4;
  if constexpr (GELU_OUT) {
    u16* Oe = (u16*)Out + (size_t)e * (size_t)CAP * N;
#pragma unroll
    for (int j = 0; j < 8; ++j) {
      int m = mb + j * 16;
#pragma unroll
      for (int i = 0; i < 4; ++i) {
        int n = nb + i * 16;
        float4 bv = *(const float4*)(be + n);
        ushort4 o;
        o.x = f2bf(gelu_erf(acc[j][i][0] + bv.x));
        o.y = f2bf(gelu_erf(acc[j][i][1] + bv.y));
        o.z = f2bf(gelu_erf(acc[j][i][2] + bv.z));
        o.w = f2bf(gelu_erf(acc[j][i][3] + bv.w));
        *(ushort4*)(Oe + (size_t)m * N + n) = o;
      }
    }
  } else {
    float* Oe = (float*)Out + (size_t)e * (size_t)CAP * N;
#pragma unroll
    for (int j = 0; j < 8; ++j) {
      int m = mb + j * 16;
#pragma unroll
      for (int i = 0; i < 4; ++i) {
        int n = nb + i * 16;
        float4 bv = *(const float4*)(be + n);
        float4 o;
        o.x = acc[j][i][0] + bv.x;
        o.y = acc[j][i][1] + bv.y;
        o.z = acc[j][i][2] + bv.z;
        o.w = acc[j][i][3] + bv.w;
        *(float4*)(Oe + (size_t)m * N + n) = o;
      }
    }
  }
}

extern "C" void kernel_launch(void* const* d_in, const int* in_sizes, int n_in,
                              void* d_out, int out_size, void* d_ws, size_t ws_size,
                              hipStream_t stream) {
  const float* x  = (const float*)d_in[0];
  // d_in[1] = expert_size (equal splits by construction; unused)
  const float* w1 = (const float*)d_in[2];
  const float* b1 = (const float*)d_in[3];
  const float* w2 = (const float*)d_in[4];
  const float* b2 = (const float*)d_in[5];
  float* out = (float*)d_out;

  char* wsp = (char*)d_ws;
  u16* x_bf = (u16*)(wsp);                             // 64 MiB
  u16* w1t  = (u16*)(wsp + (size_t)67108864);          // 64 MiB  [E][DHID][DIN]
  u16* w2t  = (u16*)(wsp + (size_t)134217728);         // 64 MiB  [E][DOUT][DHID]
  u16* h    = (u16*)(wsp + (size_t)201326592);         // 256 MiB [NTOK][DHID]

  // allow 128 KiB dynamic LDS (no-op if already set; not a stream op, capture-safe)
  hipFuncSetAttribute(reinterpret_cast<const void*>(moe_gemm256_kernel<DIN, DHID, true>),
                      hipFuncAttributeMaxDynamicSharedMemorySize, 131072);
  hipFuncSetAttribute(reinterpret_cast<const void*>(moe_gemm256_kernel<DHID, DOUTD, false>),
                      hipFuncAttributeMaxDynamicSharedMemorySize, 131072);

  convert_bf16_kernel<<<(NTOK * DIN) / (256 * 8), 256, 0, stream>>>(x, x_bf);
  transpose_bf16_kernel<<<dim3(DHID / 64, DIN / 64, NE), 256, 0, stream>>>(w1, w1t, DIN, DHID);
  transpose_bf16_kernel<<<dim3(DOUTD / 64, DHID / 64, NE), 256, 0, stream>>>(w2, w2t, DHID, DOUTD);

  moe_gemm256_kernel<DIN, DHID, true>
      <<<dim3(NE * (CAP / 256) * (DHID / 256)), 512, 131072, stream>>>(x_bf, w1t, b1, h);
  moe_gemm256_kernel<DHID, DOUTD, false>
      <<<dim3(NE * (CAP / 256) * (DOUTD / 256)), 512, 131072, stream>>>(h, w2t, b2, out);
}